// Round 2
// 246.805 us; speedup vs baseline: 1.0535x; 1.0535x over previous
//
#include <hip/hip_runtime.h>
#include <hip/hip_bf16.h>

// tanh(X @ W^T + b): M=131072, N=K=256, fp32 in/out.
// R5b: one block = 32-row chunk x ALL 256 cols. 4 waves, each wave holds its
// 64-col W-fragment set in 128 VGPRs (loaded once per block). X staged once
// into block-shared LDS (dbuf), chunk-deep global->reg prefetch with raw
// s_barrier + manual lgkmcnt (no vmcnt drain at barriers). 512 persistent
// blocks x 8 chunks, 2 blocks/CU. Nontemporal Y stores (ext-vector type).

#define HIDDEN 256
#define M_TOTAL (16 * 8192)
#define NBLK 512
#define CHUNKS_PER_BLK ((M_TOTAL / 32) / NBLK)   // 8

using bf16x8 = __attribute__((ext_vector_type(8))) __bf16;
using bf16x4 = __attribute__((ext_vector_type(4))) __bf16;
using f32x4  = __attribute__((ext_vector_type(4))) float;

__device__ __forceinline__ bf16x4 cvt4(float4 v) {
    bf16x4 r;
    r[0] = (__bf16)v.x; r[1] = (__bf16)v.y;
    r[2] = (__bf16)v.z; r[3] = (__bf16)v.w;
    return r;
}

// WF[((nb*8 + c)*4 + t)*512 + lane*8 + j] =
//   bf16( W[(nb*64 + t*16 + (lane&15))*256 + c*32 + (lane>>4)*8 + j] )
__global__ __launch_bounds__(256) void wfrag_kernel(const float* __restrict__ W,
                                                    __bf16* __restrict__ WF) {
    const int gid  = blockIdx.x * 256 + threadIdx.x;   // 0..8191
    const int lane = gid & 63;
    const int t    = (gid >> 6) & 3;
    const int c    = (gid >> 8) & 7;
    const int nb   = gid >> 11;
    const int lr = lane & 15, q = lane >> 4;
    const float* src = W + (size_t)(nb * 64 + t * 16 + lr) * HIDDEN + c * 32 + q * 8;
    float4 lo = *(const float4*)src;
    float4 hi = *(const float4*)(src + 4);
    bf16x8 v;
    v[0] = (__bf16)lo.x; v[1] = (__bf16)lo.y; v[2] = (__bf16)lo.z; v[3] = (__bf16)lo.w;
    v[4] = (__bf16)hi.x; v[5] = (__bf16)hi.y; v[6] = (__bf16)hi.z; v[7] = (__bf16)hi.w;
    *(bf16x8*)(WF + (size_t)gid * 8) = v;
}

__global__ __launch_bounds__(256, 2) void rotor_kernel(const float* __restrict__ X,
                                                       const __bf16* __restrict__ WF,
                                                       const float* __restrict__ bias,
                                                       float* __restrict__ Y) {
    // LDS: X double-buffer 2 x 8192 bf16 (32 KB, a-frag layout) +
    //      per-wave epilogue tile 4 x 4352 B = 50176 B total.
    __shared__ __align__(16) unsigned char lds_raw[2 * 16384 + 4 * 4352];
    __bf16* sXb = (__bf16*)lds_raw;
    float*  sO  = (float*)(lds_raw + 32768 + (threadIdx.x >> 6) * 4352);

    const int tid  = threadIdx.x;
    const int lane = tid & 63;
    const int wave = tid >> 6;
    const int lr = lane & 15, q = lane >> 4;

    // ---- X staging map: thread owns row (tid>>3), k-quad (tid&7), 8 chunks ----
    const int xrow = tid >> 3;   // 0..31
    const int xc   = tid & 7;    // k base = xc*4 within each 32-k chunk
    int woff[8];
#pragma unroll
    for (int j = 0; j < 8; ++j)
        woff[j] = j * 1024 + (xrow >> 4) * 512 + ((xc >> 1) * 16 + (xrow & 15)) * 8 + (xc & 1) * 4;

    const size_t blk_row0 = (size_t)blockIdx.x * (CHUNKS_PER_BLK * 32);
    const float* xbase = X + (blk_row0 + xrow) * HIDDEN + xc * 4;

    // ---- prefetch chunk 0 ----
    float4 xr[8];
#pragma unroll
    for (int j = 0; j < 8; ++j) xr[j] = *(const float4*)(xbase + j * 32);

    // ---- this wave's full 64-col W fragment set: 32 x bf16x8 = 128 VGPRs ----
    const __bf16* wf = WF + (size_t)wave * (8 * 4 * 512) + lane * 8;
    bf16x8 bW[8][4];
#pragma unroll
    for (int c = 0; c < 8; ++c)
#pragma unroll
        for (int t = 0; t < 4; ++t)
            bW[c][t] = *(const bf16x8*)(wf + (c * 4 + t) * 512);

    float bv[4];
#pragma unroll
    for (int t = 0; t < 4; ++t) bv[t] = bias[wave * 64 + t * 16 + lr];

    // ---- stage chunk 0 ----
#pragma unroll
    for (int j = 0; j < 8; ++j) *(bf16x4*)(sXb + woff[j]) = cvt4(xr[j]);
    asm volatile("s_waitcnt lgkmcnt(0)" ::: "memory");
    __builtin_amdgcn_s_barrier();
    asm volatile("" ::: "memory");

#pragma unroll 1
    for (int it = 0; it < CHUNKS_PER_BLK; ++it) {
        const int cur = it & 1;

        // prefetch next chunk (consumed by ds_write after compute+epilogue)
        if (it + 1 < CHUNKS_PER_BLK) {
            const float* xs = xbase + (size_t)(it + 1) * 32 * HIDDEN;
#pragma unroll
            for (int j = 0; j < 8; ++j) xr[j] = *(const float4*)(xs + j * 32);
        }

        f32x4 acc[2][4];
#pragma unroll
        for (int m = 0; m < 2; ++m)
#pragma unroll
            for (int t = 0; t < 4; ++t)
                acc[m][t] = (f32x4){0.f, 0.f, 0.f, 0.f};

        const __bf16* sX = sXb + cur * 8192;
#pragma unroll
        for (int c = 0; c < 8; ++c) {
            const __bf16* ab = sX + c * 1024 + lane * 8;
            bf16x8 a0 = *(const bf16x8*)ab;
            bf16x8 a1 = *(const bf16x8*)(ab + 512);
            acc[0][0] = __builtin_amdgcn_mfma_f32_16x16x32_bf16(a0, bW[c][0], acc[0][0], 0, 0, 0);
            acc[0][1] = __builtin_amdgcn_mfma_f32_16x16x32_bf16(a0, bW[c][1], acc[0][1], 0, 0, 0);
            acc[0][2] = __builtin_amdgcn_mfma_f32_16x16x32_bf16(a0, bW[c][2], acc[0][2], 0, 0, 0);
            acc[0][3] = __builtin_amdgcn_mfma_f32_16x16x32_bf16(a0, bW[c][3], acc[0][3], 0, 0, 0);
            acc[1][0] = __builtin_amdgcn_mfma_f32_16x16x32_bf16(a1, bW[c][0], acc[1][0], 0, 0, 0);
            acc[1][1] = __builtin_amdgcn_mfma_f32_16x16x32_bf16(a1, bW[c][1], acc[1][1], 0, 0, 0);
            acc[1][2] = __builtin_amdgcn_mfma_f32_16x16x32_bf16(a1, bW[c][2], acc[1][2], 0, 0, 0);
            acc[1][3] = __builtin_amdgcn_mfma_f32_16x16x32_bf16(a1, bW[c][3], acc[1][3], 0, 0, 0);
        }

        // ---- epilogue: bias+tanh, per-wave LDS shuffle, coalesced nt stores ----
        float* yb = Y + (blk_row0 + (size_t)it * 32) * HIDDEN + wave * 64;
#pragma unroll
        for (int m = 0; m < 2; ++m) {
#pragma unroll
            for (int t = 0; t < 4; ++t)
#pragma unroll
                for (int r = 0; r < 4; ++r) {
                    float z = acc[m][t][r] + bv[t];
                    z = fminf(fmaxf(z, -10.f), 10.f);
                    const float e2 = __expf(2.0f * z);
                    sO[(q * 4 + r) * 68 + t * 16 + lr] = __fdividef(e2 - 1.0f, e2 + 1.0f);
                }
#pragma unroll
            for (int j = 0; j < 4; ++j) {
                f32x4 v = *(const f32x4*)(sO + (j * 4 + q) * 68 + lr * 4);
                __builtin_nontemporal_store(v,
                    (f32x4*)(yb + (size_t)(m * 16 + j * 4 + q) * HIDDEN + lr * 4));
            }
        }

        // ---- stage next chunk into the other buffer ----
        if (it + 1 < CHUNKS_PER_BLK) {
            __bf16* sW = sXb + (cur ^ 1) * 8192;
#pragma unroll
            for (int j = 0; j < 8; ++j) *(bf16x4*)(sW + woff[j]) = cvt4(xr[j]);
        }
        asm volatile("s_waitcnt lgkmcnt(0)" ::: "memory");
        __builtin_amdgcn_s_barrier();
        asm volatile("" ::: "memory");
    }
}

extern "C" void kernel_launch(void* const* d_in, const int* in_sizes, int n_in,
                              void* d_out, int out_size, void* d_ws, size_t ws_size,
                              hipStream_t stream) {
    const float* X    = (const float*)d_in[0];
    const float* W    = (const float*)d_in[1];
    const float* bias = (const float*)d_in[2];
    float* Y          = (float*)d_out;
    __bf16* WF        = (__bf16*)d_ws;     // 65536 bf16 = 128 KB

    wfrag_kernel<<<dim3(32), dim3(256), 0, stream>>>(W, WF);
    rotor_kernel<<<dim3(NBLK), dim3(256), 0, stream>>>(X, WF, bias, Y);
}